// Round 5
// baseline (429.776 us; speedup 1.0000x reference)
//
#include <hip/hip_runtime.h>
#include <hip/hip_bf16.h>

#define N_NODES 100000
#define N_EDGES 1600000
#define N_ROIS  400
#define RKP     416      // 400 padded to 13*32
#define HID     128
#define N_GRAPHS 512
#define NOUT    2
#define NBUCK   391      // ceil(N_NODES/256), bucket = node >> 8
#define BCAP    8192     // per-bucket edge capacity (mean 4092, sigma 64)
#define ECH     4096     // edges per bucket_k block
#define NPW     16       // nodes per gather wave

typedef __attribute__((ext_vector_type(8))) short short8;
typedef __attribute__((ext_vector_type(4))) float f32x4;

static __device__ __forceinline__ unsigned short f2bf(float f) {
  unsigned u = __float_as_uint(f);
  u += 0x7fffu + ((u >> 16) & 1u);   // RNE
  return (unsigned short)(u >> 16);
}
static __device__ __forceinline__ float blo(unsigned int u) {
  return __uint_as_float(u << 16);
}
static __device__ __forceinline__ float bhi(unsigned int u) {
  return __uint_as_float(u & 0xffff0000u);
}

// ---- single-pass bucket append: pairs[b*BCAP + rank] = (row<<8 | col&255) ----
__global__ __launch_bounds__(256) void bucket_k(
    const int* __restrict__ row, const int* __restrict__ col,
    int* __restrict__ bcnt, unsigned int* __restrict__ pairs) {
  __shared__ int hist[NBUCK];
  __shared__ int base[NBUCK];
  int t = threadIdx.x;
  for (int b = t; b < NBUCK; b += 256) hist[b] = 0;
  __syncthreads();
  int e0 = blockIdx.x * ECH;
  unsigned int pk[16];
  int bk[16], rk[16];
#pragma unroll
  for (int i = 0; i < 16; ++i) {
    int e = e0 + t + i * 256;
    if (e < N_EDGES) {
      int r = row[e], c = col[e];
      bk[i] = c >> 8;
      pk[i] = ((unsigned)r << 8) | (unsigned)(c & 255);
      rk[i] = atomicAdd(&hist[bk[i]], 1);   // LDS atomic: local rank
    } else bk[i] = -1;
  }
  __syncthreads();
  for (int b = t; b < NBUCK; b += 256)
    base[b] = (hist[b] > 0) ? atomicAdd(&bcnt[b], hist[b]) : 0;
  __syncthreads();
#pragma unroll
  for (int i = 0; i < 16; ++i)
    if (bk[i] >= 0) {
      int p = base[bk[i]] + rk[i];
      if (p < BCAP) pairs[(size_t)bk[i] * BCAP + p] = pk[i];
    }
}

// ---- per-bucket CSR build entirely in LDS ----
__global__ __launch_bounds__(256) void csr_build_k(
    const unsigned int* __restrict__ pairs, const int* __restrict__ bcnt,
    int* __restrict__ csr_row, int* __restrict__ offs, int* __restrict__ cnt,
    float* __restrict__ dinv) {
  __shared__ unsigned int ep[BCAP];
  __shared__ int h[256];
  __shared__ int sc[256];
  __shared__ int cur[256];
  int b = blockIdx.x;
  int t = threadIdx.x;
  int m = min(bcnt[b], BCAP);
  size_t base = (size_t)b * BCAP;
  for (int j = t; j < m; j += 256) ep[j] = pairs[base + j];
  h[t] = 0;
  __syncthreads();
  for (int j = t; j < m; j += 256) atomicAdd(&h[ep[j] & 255u], 1);
  __syncthreads();
  int myc = h[t];
  sc[t] = myc;
  __syncthreads();
  for (int off = 1; off < 256; off <<= 1) {
    int v = (t >= off) ? sc[t - off] : 0;
    __syncthreads();
    sc[t] += v;
    __syncthreads();
  }
  int loff = sc[t] - myc;     // exclusive scan
  cur[t] = loff;
  int node = b * 256 + t;
  if (node < N_NODES) {
    cnt[node] = myc;
    offs[node] = (int)base + loff;
    dinv[node] = rsqrtf((float)(myc + 1));
  }
  __syncthreads();
  for (int j = t; j < m; j += 256) {
    unsigned int e = ep[j];
    int pos = atomicAdd(&cur[e & 255u], 1);   // LDS atomic
    csr_row[base + pos] = (int)(e >> 8);
  }
}

// ---- W [400][128] fp32 -> Wt [128][416] bf16 (transposed, zero-padded K) ----
__global__ void prep_wt_k(const float* __restrict__ W, unsigned short* __restrict__ Wt) {
  int idx = blockIdx.x * blockDim.x + threadIdx.x;
  if (idx < HID * RKP) {
    int n = idx / RKP, k = idx - n * RKP;
    float v = (k < N_ROIS) ? W[k * HID + n] : 0.f;
    Wt[idx] = f2bf(v);
  }
}

// ---- h' = (x@W) * dinv[row]: fully register-resident MFMA, NO LDS, NO barriers.
// A and B frags are contiguous 16B global loads (A: x rows; B: Wt rows, L2-resident).
// Software-pipelined one k-step ahead with explicit double register sets.
// 16x16x32 bf16 frags: A[m=lane&15][k=(lane>>4)*8+j]; B[k=(lane>>4)*8+j][n=lane&15];
// D[row=(lane>>4)*4+r][col=lane&15]
__global__ __launch_bounds__(256) void gemm_k(
    const float* __restrict__ x, const unsigned short* __restrict__ Wt,
    const float* __restrict__ dinv, unsigned short* __restrict__ hp) {
  int t = threadIdx.x;
  int lane = t & 63;
  int wv = t >> 6;
  int row0 = blockIdx.x * 64;
  int mrow = lane & 15;
  int kgrp = lane >> 4;
  int grow_r = row0 + wv * 16 + mrow;
  const float* xp = x + (size_t)min(grow_r, N_NODES - 1) * N_ROIS + kgrp * 8;
  const unsigned short* wp = Wt + (size_t)mrow * RKP + kgrp * 8;
  int klim = N_ROIS - kgrp * 8;   // A-load valid while s*32 < klim

  f32x4 acc[8];
#pragma unroll
  for (int i = 0; i < 8; ++i) acc[i] = (f32x4){0.f, 0.f, 0.f, 0.f};

#define LOAD_A(dst, s)                                            \
  do {                                                            \
    if ((s) * 32 < klim) {                                        \
      float4 f0 = *(const float4*)(xp + (s) * 32);                \
      float4 f1 = *(const float4*)(xp + (s) * 32 + 4);            \
      dst[0] = (short)f2bf(f0.x); dst[1] = (short)f2bf(f0.y);     \
      dst[2] = (short)f2bf(f0.z); dst[3] = (short)f2bf(f0.w);     \
      dst[4] = (short)f2bf(f1.x); dst[5] = (short)f2bf(f1.y);     \
      dst[6] = (short)f2bf(f1.z); dst[7] = (short)f2bf(f1.w);     \
    } else {                                                      \
      dst = (short8){0, 0, 0, 0, 0, 0, 0, 0};                     \
    }                                                             \
  } while (0)

#define LOAD_B(dst, s)                                                     \
  do {                                                                     \
    _Pragma("unroll")                                                      \
    for (int nt = 0; nt < 8; ++nt)                                         \
      dst[nt] = *(const short8*)(wp + (size_t)nt * 16 * RKP + (s) * 32);   \
  } while (0)

#define MFMA_SET(a, bset)                                                  \
  do {                                                                     \
    _Pragma("unroll")                                                      \
    for (int nt = 0; nt < 8; ++nt)                                         \
      acc[nt] = __builtin_amdgcn_mfma_f32_16x16x32_bf16(a, bset[nt], acc[nt], 0, 0, 0); \
  } while (0)

  short8 a0, a1, b0[8], b1[8];
  LOAD_A(a0, 0);
  LOAD_B(b0, 0);
#pragma unroll 1
  for (int s = 0; s + 2 <= 13; s += 2) {
    LOAD_A(a1, s + 1);
    LOAD_B(b1, s + 1);
    MFMA_SET(a0, b0);
    if (s + 2 < 13) {
      LOAD_A(a0, s + 2);
      LOAD_B(b0, s + 2);
    }
    MFMA_SET(a1, b1);
  }
  MFMA_SET(a0, b0);   // tail step s=12 (prefetched in last loop iteration)
#undef LOAD_A
#undef LOAD_B
#undef MFMA_SET

#pragma unroll
  for (int r = 0; r < 4; ++r) {
    int grow = row0 + wv * 16 + kgrp * 4 + r;
    if (grow < N_NODES) {
      float di = dinv[grow];
      unsigned short* op = hp + (size_t)grow * HID + mrow;
#pragma unroll
      for (int nt = 0; nt < 8; ++nt) {
        op[nt * 16] = f2bf(di * acc[nt][r]);
      }
    }
  }
}

// ---- aggregation: quadrant-parallel edges, dwordx4 row loads, shuffle reduce,
// register-resident pooling flushed on graph change ----
__global__ __launch_bounds__(256) void gather_k(
    const unsigned short* __restrict__ hp, const int* __restrict__ csr_row,
    const int* __restrict__ offs, const int* __restrict__ cnt,
    const float* __restrict__ dinv, const int* __restrict__ batch,
    const float* __restrict__ bias, unsigned int* __restrict__ pooled_bits) {
  int wave = (blockIdx.x * blockDim.x + threadIdx.x) >> 6;
  int lane = threadIdx.x & 63;
  int q = lane >> 4;        // quadrant: edge j % 4
  int d = lane & 15;        // dim slot: dims d*8 .. d*8+7
  int n0 = wave * NPW;
  if (n0 >= N_NODES) return;
  int nend = min(n0 + NPW, N_NODES);
  float4 bb0 = *(const float4*)(bias + d * 8);
  float4 bb1 = *(const float4*)(bias + d * 8 + 4);
  float rm[8];
#pragma unroll
  for (int k = 0; k < 8; ++k) rm[k] = 0.f;
  int cur_g = batch[n0];

  for (int i = n0; i < nend; ++i) {
    int start = offs[i];
    int m = cnt[i];
    float a[8];
    if (q == 0) {   // self-loop row, quadrant 0 only
      uint4 u = *(const uint4*)(hp + (size_t)i * HID + d * 8);
      a[0] = blo(u.x); a[1] = bhi(u.x); a[2] = blo(u.y); a[3] = bhi(u.y);
      a[4] = blo(u.z); a[5] = bhi(u.z); a[6] = blo(u.w); a[7] = bhi(u.w);
    } else {
#pragma unroll
      for (int k = 0; k < 8; ++k) a[k] = 0.f;
    }
    for (int j = q; j < m; j += 4) {
      int s = csr_row[start + j];
      uint4 u = *(const uint4*)(hp + (size_t)s * HID + d * 8);
      a[0] += blo(u.x); a[1] += bhi(u.x); a[2] += blo(u.y); a[3] += bhi(u.y);
      a[4] += blo(u.z); a[5] += bhi(u.z); a[6] += blo(u.w); a[7] += bhi(u.w);
    }
#pragma unroll
    for (int k = 0; k < 8; ++k) {   // butterfly over quadrants (lanes ^16, ^32)
      a[k] += __shfl_xor(a[k], 16, 64);
      a[k] += __shfl_xor(a[k], 32, 64);
    }
    float di = dinv[i];
    float p[8];
    p[0] = fmaxf(fmaf(di, a[0], bb0.x), 0.f);
    p[1] = fmaxf(fmaf(di, a[1], bb0.y), 0.f);
    p[2] = fmaxf(fmaf(di, a[2], bb0.z), 0.f);
    p[3] = fmaxf(fmaf(di, a[3], bb0.w), 0.f);
    p[4] = fmaxf(fmaf(di, a[4], bb1.x), 0.f);
    p[5] = fmaxf(fmaf(di, a[5], bb1.y), 0.f);
    p[6] = fmaxf(fmaf(di, a[6], bb1.z), 0.f);
    p[7] = fmaxf(fmaf(di, a[7], bb1.w), 0.f);
    int g = batch[i];
    if (g != cur_g) {               // wave-uniform
      if (q == 0) {
#pragma unroll
        for (int k = 0; k < 8; ++k)
          atomicMax(&pooled_bits[cur_g * HID + d * 8 + k], __float_as_uint(rm[k]));
      }
#pragma unroll
      for (int k = 0; k < 8; ++k) rm[k] = 0.f;
      cur_g = g;
    }
#pragma unroll
    for (int k = 0; k < 8; ++k) rm[k] = fmaxf(rm[k], p[k]);
  }
  if (q == 0) {
#pragma unroll
    for (int k = 0; k < 8; ++k)
      atomicMax(&pooled_bits[cur_g * HID + d * 8 + k], __float_as_uint(rm[k]));
  }
}

// ---- logits = pooled @ lin_W + lin_b ----
__global__ void logits_k(const float* __restrict__ pooled, const float* __restrict__ lin_W,
                         const float* __restrict__ lin_b, float* __restrict__ out) {
  int t = blockIdx.x * blockDim.x + threadIdx.x;
  if (t < N_GRAPHS * NOUT) {
    int g = t >> 1, o = t & 1;
    float s = lin_b[o];
    const float* pg = pooled + g * HID;
#pragma unroll 8
    for (int k = 0; k < HID; ++k) s = fmaf(pg[k], lin_W[k * NOUT + o], s);
    out[t] = s;
  }
}

extern "C" void kernel_launch(void* const* d_in, const int* in_sizes, int n_in,
                              void* d_out, int out_size, void* d_ws, size_t ws_size,
                              hipStream_t stream) {
  (void)in_sizes; (void)n_in; (void)ws_size;
  const float* x     = (const float*)d_in[0];
  const int*   ei    = (const int*)d_in[1];
  const int*   row   = ei;             // sources
  const int*   col   = ei + N_EDGES;   // targets
  const int*   batch = (const int*)d_in[2];
  const float* W     = (const float*)d_in[3];
  const float* b     = (const float*)d_in[4];
  const float* lin_W = (const float*)d_in[5];
  const float* lin_b = (const float*)d_in[6];
  float* out = (float*)d_out;

  // workspace layout (pairs dead after csr_build_k -> hp aliases it)
  char* ws = (char*)d_ws;
  int*   bcnt    = (int*)(ws + 0);               //   4,096 B (391 used)
  int*   offs    = (int*)(ws + 4096);            // 400,000 B
  int*   cnt     = (int*)(ws + 404096);          // 400,000 B
  float* dinv    = (float*)(ws + 804096);        // 400,000 B
  unsigned short* Wt = (unsigned short*)(ws + 1204096);   // 106,496 B
  int*   csr_row = (int*)(ws + 1310720);         // 391*8192*4 = 12,812,288 B
  unsigned int* pairs = (unsigned int*)(ws + 14123008);   // 12,812,288 B
  unsigned short* hp  = (unsigned short*)(ws + 14123008); // 25,600,000 B (aliases pairs)

  hipMemsetAsync(bcnt, 0, NBUCK * sizeof(int), stream);
  hipMemsetAsync(d_out, 0, (size_t)out_size * sizeof(float), stream);

  bucket_k<<<(N_EDGES + ECH - 1) / ECH, 256, 0, stream>>>(row, col, bcnt, pairs);
  csr_build_k<<<NBUCK, 256, 0, stream>>>(pairs, bcnt, csr_row, offs, cnt, dinv);
  prep_wt_k<<<(HID * RKP + 255) / 256, 256, 0, stream>>>(W, Wt);
  gemm_k<<<(N_NODES + 63) / 64, 256, 0, stream>>>(x, Wt, dinv, hp);
  {
    int waves = (N_NODES + NPW - 1) / NPW;             // 6250
    int blocks = (waves * 64 + 255) / 256;             // 1563
    gather_k<<<blocks, 256, 0, stream>>>(
        hp, csr_row, offs, cnt, dinv, batch, b,
        (unsigned int*)(out + N_GRAPHS * NOUT));
  }
  logits_k<<<(N_GRAPHS * NOUT + 255) / 256, 256, 0, stream>>>(
      out + N_GRAPHS * NOUT, lin_W, lin_b, out);
}

// Round 6
// 391.648 us; speedup vs baseline: 1.0974x; 1.0974x over previous
//
#include <hip/hip_runtime.h>
#include <hip/hip_bf16.h>

#define N_NODES 100000
#define N_EDGES 1600000
#define N_ROIS  400
#define RKP     416      // 400 padded to 13*32
#define HID     128
#define N_GRAPHS 512
#define NOUT    2
#define NBUCK   391      // ceil(N_NODES/256), bucket = node >> 8
#define BCAP    8192     // per-bucket edge capacity (mean 4092, sigma 64)
#define ECH     4096     // edges per bucket_k block
#define NPW     16       // nodes per gather wave

typedef __attribute__((ext_vector_type(8))) short short8;
typedef __attribute__((ext_vector_type(4))) float f32x4;

static __device__ __forceinline__ unsigned short f2bf(float f) {
  unsigned u = __float_as_uint(f);
  u += 0x7fffu + ((u >> 16) & 1u);   // RNE
  return (unsigned short)(u >> 16);
}
static __device__ __forceinline__ float blo(unsigned int u) {
  return __uint_as_float(u << 16);
}
static __device__ __forceinline__ float bhi(unsigned int u) {
  return __uint_as_float(u & 0xffff0000u);
}

// ---- single-pass bucket append: pairs[b*BCAP + rank] = (row<<8 | col&255) ----
__global__ __launch_bounds__(256) void bucket_k(
    const int* __restrict__ row, const int* __restrict__ col,
    int* __restrict__ bcnt, unsigned int* __restrict__ pairs) {
  __shared__ int hist[NBUCK];
  __shared__ int base[NBUCK];
  int t = threadIdx.x;
  for (int b = t; b < NBUCK; b += 256) hist[b] = 0;
  __syncthreads();
  int e0 = blockIdx.x * ECH;
  unsigned int pk[16];
  int bk[16], rk[16];
#pragma unroll
  for (int i = 0; i < 16; ++i) {
    int e = e0 + t + i * 256;
    if (e < N_EDGES) {
      int r = row[e], c = col[e];
      bk[i] = c >> 8;
      pk[i] = ((unsigned)r << 8) | (unsigned)(c & 255);
      rk[i] = atomicAdd(&hist[bk[i]], 1);   // LDS atomic: local rank
    } else bk[i] = -1;
  }
  __syncthreads();
  for (int b = t; b < NBUCK; b += 256)
    base[b] = (hist[b] > 0) ? atomicAdd(&bcnt[b], hist[b]) : 0;
  __syncthreads();
#pragma unroll
  for (int i = 0; i < 16; ++i)
    if (bk[i] >= 0) {
      int p = base[bk[i]] + rk[i];
      if (p < BCAP) pairs[(size_t)bk[i] * BCAP + p] = pk[i];
    }
}

// ---- per-bucket CSR build entirely in LDS ----
__global__ __launch_bounds__(256) void csr_build_k(
    const unsigned int* __restrict__ pairs, const int* __restrict__ bcnt,
    int* __restrict__ csr_row, int* __restrict__ offs, int* __restrict__ cnt,
    float* __restrict__ dinv) {
  __shared__ unsigned int ep[BCAP];
  __shared__ int h[256];
  __shared__ int sc[256];
  __shared__ int cur[256];
  int b = blockIdx.x;
  int t = threadIdx.x;
  int m = min(bcnt[b], BCAP);
  size_t base = (size_t)b * BCAP;
  for (int j = t; j < m; j += 256) ep[j] = pairs[base + j];
  h[t] = 0;
  __syncthreads();
  for (int j = t; j < m; j += 256) atomicAdd(&h[ep[j] & 255u], 1);
  __syncthreads();
  int myc = h[t];
  sc[t] = myc;
  __syncthreads();
  for (int off = 1; off < 256; off <<= 1) {
    int v = (t >= off) ? sc[t - off] : 0;
    __syncthreads();
    sc[t] += v;
    __syncthreads();
  }
  int loff = sc[t] - myc;     // exclusive scan
  cur[t] = loff;
  int node = b * 256 + t;
  if (node < N_NODES) {
    cnt[node] = myc;
    offs[node] = (int)base + loff;
    dinv[node] = rsqrtf((float)(myc + 1));
  }
  __syncthreads();
  for (int j = t; j < m; j += 256) {
    unsigned int e = ep[j];
    int pos = atomicAdd(&cur[e & 255u], 1);   // LDS atomic
    csr_row[base + pos] = (int)(e >> 8);
  }
}

// ---- W [400][128] fp32 -> Wt [128][416] bf16 (transposed, zero-padded K) ----
__global__ void prep_wt_k(const float* __restrict__ W, unsigned short* __restrict__ Wt) {
  int idx = blockIdx.x * blockDim.x + threadIdx.x;
  if (idx < HID * RKP) {
    int n = idx / RKP, k = idx - n * RKP;
    float v = (k < N_ROIS) ? W[k * HID + n] : 0.f;
    Wt[idx] = f2bf(v);
  }
}

// ---- h' = (x@W) * dinv[row], bf16 MFMA, output bf16 [N][128].
// PROVEN R1-R3 structure: light LDS (16 KB) -> ~3 blocks/CU; inter-block wave
// overlap hides the 2-barrier-per-step drains (m114 mechanism). R4 (barrier-
// coupled global_load_lds dbuf) and R5 (register pipeline, no barriers, occ 26%)
// both regressed -- do not restructure this again without dispatch-level evidence.
// 16x16x32 bf16 frags: A[m=lane&15][k=(lane>>4)*8+j]; B[k][n=lane&15];
// D[row=(lane>>4)*4+r][col=lane&15]
__global__ __launch_bounds__(256) void gemm_k(
    const float* __restrict__ x, const unsigned short* __restrict__ Wt,
    const float* __restrict__ dinv, unsigned short* __restrict__ hp) {
  __shared__ __align__(16) short As[64][40];
  __shared__ __align__(16) short Bs[HID][40];
  int t = threadIdx.x;
  int lane = t & 63;
  int wv = t >> 6;
  int row0 = blockIdx.x * 64;
  int mrow = lane & 15;
  int kgrp = lane >> 4;

  f32x4 acc[8];
#pragma unroll
  for (int i = 0; i < 8; ++i) acc[i] = (f32x4){0.f, 0.f, 0.f, 0.f};

  int arow = t >> 2;
  int akofs = (t & 3) * 8;
  int brow = t >> 1;
  int bkofs = (t & 1) * 16;
  int grow_a = row0 + arow;
  const float* xp = x + (size_t)grow_a * N_ROIS;

  for (int kk = 0; kk < RKP; kk += 32) {
    short8 a8;
    if (grow_a < N_NODES && kk + akofs + 8 <= N_ROIS) {
      float4 f0 = *(const float4*)(xp + kk + akofs);
      float4 f1 = *(const float4*)(xp + kk + akofs + 4);
      a8[0] = (short)f2bf(f0.x); a8[1] = (short)f2bf(f0.y);
      a8[2] = (short)f2bf(f0.z); a8[3] = (short)f2bf(f0.w);
      a8[4] = (short)f2bf(f1.x); a8[5] = (short)f2bf(f1.y);
      a8[6] = (short)f2bf(f1.z); a8[7] = (short)f2bf(f1.w);
    } else {
#pragma unroll
      for (int u = 0; u < 8; ++u) {
        int k = kk + akofs + u;
        float f = (grow_a < N_NODES && k < N_ROIS) ? xp[k] : 0.f;
        a8[u] = (short)f2bf(f);
      }
    }
    *(short8*)&As[arow][akofs] = a8;
    const short8* wp = (const short8*)(Wt + (size_t)brow * RKP + kk + bkofs);
    *(short8*)&Bs[brow][bkofs] = wp[0];
    *(short8*)&Bs[brow][bkofs + 8] = wp[1];
    __syncthreads();

    short8 af = *(const short8*)&As[wv * 16 + mrow][kgrp * 8];
#pragma unroll
    for (int nt = 0; nt < 8; ++nt) {
      short8 bf = *(const short8*)&Bs[nt * 16 + mrow][kgrp * 8];
      acc[nt] = __builtin_amdgcn_mfma_f32_16x16x32_bf16(af, bf, acc[nt], 0, 0, 0);
    }
    __syncthreads();
  }

#pragma unroll
  for (int r = 0; r < 4; ++r) {
    int grow = row0 + wv * 16 + kgrp * 4 + r;
    if (grow < N_NODES) {
      float di = dinv[grow];
      unsigned short* op = hp + (size_t)grow * HID + mrow;
#pragma unroll
      for (int nt = 0; nt < 8; ++nt) {
        op[nt * 16] = f2bf(di * acc[nt][r]);
      }
    }
  }
}

// ---- aggregation: quadrant-parallel edges, dwordx4 row loads, shuffle reduce,
// register-resident pooling flushed on graph change ----
__global__ __launch_bounds__(256) void gather_k(
    const unsigned short* __restrict__ hp, const int* __restrict__ csr_row,
    const int* __restrict__ offs, const int* __restrict__ cnt,
    const float* __restrict__ dinv, const int* __restrict__ batch,
    const float* __restrict__ bias, unsigned int* __restrict__ pooled_bits) {
  int wave = (blockIdx.x * blockDim.x + threadIdx.x) >> 6;
  int lane = threadIdx.x & 63;
  int q = lane >> 4;        // quadrant: edge j % 4
  int d = lane & 15;        // dim slot: dims d*8 .. d*8+7
  int n0 = wave * NPW;
  if (n0 >= N_NODES) return;
  int nend = min(n0 + NPW, N_NODES);
  float4 bb0 = *(const float4*)(bias + d * 8);
  float4 bb1 = *(const float4*)(bias + d * 8 + 4);
  float rm[8];
#pragma unroll
  for (int k = 0; k < 8; ++k) rm[k] = 0.f;
  int cur_g = batch[n0];

  for (int i = n0; i < nend; ++i) {
    int start = offs[i];
    int m = cnt[i];
    float a[8];
    if (q == 0) {   // self-loop row, quadrant 0 only
      uint4 u = *(const uint4*)(hp + (size_t)i * HID + d * 8);
      a[0] = blo(u.x); a[1] = bhi(u.x); a[2] = blo(u.y); a[3] = bhi(u.y);
      a[4] = blo(u.z); a[5] = bhi(u.z); a[6] = blo(u.w); a[7] = bhi(u.w);
    } else {
#pragma unroll
      for (int k = 0; k < 8; ++k) a[k] = 0.f;
    }
    for (int j = q; j < m; j += 4) {
      int s = csr_row[start + j];
      uint4 u = *(const uint4*)(hp + (size_t)s * HID + d * 8);
      a[0] += blo(u.x); a[1] += bhi(u.x); a[2] += blo(u.y); a[3] += bhi(u.y);
      a[4] += blo(u.z); a[5] += bhi(u.z); a[6] += blo(u.w); a[7] += bhi(u.w);
    }
#pragma unroll
    for (int k = 0; k < 8; ++k) {   // butterfly over quadrants (lanes ^16, ^32)
      a[k] += __shfl_xor(a[k], 16, 64);
      a[k] += __shfl_xor(a[k], 32, 64);
    }
    float di = dinv[i];
    float p[8];
    p[0] = fmaxf(fmaf(di, a[0], bb0.x), 0.f);
    p[1] = fmaxf(fmaf(di, a[1], bb0.y), 0.f);
    p[2] = fmaxf(fmaf(di, a[2], bb0.z), 0.f);
    p[3] = fmaxf(fmaf(di, a[3], bb0.w), 0.f);
    p[4] = fmaxf(fmaf(di, a[4], bb1.x), 0.f);
    p[5] = fmaxf(fmaf(di, a[5], bb1.y), 0.f);
    p[6] = fmaxf(fmaf(di, a[6], bb1.z), 0.f);
    p[7] = fmaxf(fmaf(di, a[7], bb1.w), 0.f);
    int g = batch[i];
    if (g != cur_g) {               // wave-uniform
      if (q == 0) {
#pragma unroll
        for (int k = 0; k < 8; ++k)
          atomicMax(&pooled_bits[cur_g * HID + d * 8 + k], __float_as_uint(rm[k]));
      }
#pragma unroll
      for (int k = 0; k < 8; ++k) rm[k] = 0.f;
      cur_g = g;
    }
#pragma unroll
    for (int k = 0; k < 8; ++k) rm[k] = fmaxf(rm[k], p[k]);
  }
  if (q == 0) {
#pragma unroll
    for (int k = 0; k < 8; ++k)
      atomicMax(&pooled_bits[cur_g * HID + d * 8 + k], __float_as_uint(rm[k]));
  }
}

// ---- logits = pooled @ lin_W + lin_b ----
__global__ void logits_k(const float* __restrict__ pooled, const float* __restrict__ lin_W,
                         const float* __restrict__ lin_b, float* __restrict__ out) {
  int t = blockIdx.x * blockDim.x + threadIdx.x;
  if (t < N_GRAPHS * NOUT) {
    int g = t >> 1, o = t & 1;
    float s = lin_b[o];
    const float* pg = pooled + g * HID;
#pragma unroll 8
    for (int k = 0; k < HID; ++k) s = fmaf(pg[k], lin_W[k * NOUT + o], s);
    out[t] = s;
  }
}

extern "C" void kernel_launch(void* const* d_in, const int* in_sizes, int n_in,
                              void* d_out, int out_size, void* d_ws, size_t ws_size,
                              hipStream_t stream) {
  (void)in_sizes; (void)n_in; (void)ws_size;
  const float* x     = (const float*)d_in[0];
  const int*   ei    = (const int*)d_in[1];
  const int*   row   = ei;             // sources
  const int*   col   = ei + N_EDGES;   // targets
  const int*   batch = (const int*)d_in[2];
  const float* W     = (const float*)d_in[3];
  const float* b     = (const float*)d_in[4];
  const float* lin_W = (const float*)d_in[5];
  const float* lin_b = (const float*)d_in[6];
  float* out = (float*)d_out;

  // workspace layout (pairs dead after csr_build_k -> hp aliases it)
  char* ws = (char*)d_ws;
  int*   bcnt    = (int*)(ws + 0);               //   4,096 B (391 used)
  int*   offs    = (int*)(ws + 4096);            // 400,000 B
  int*   cnt     = (int*)(ws + 404096);          // 400,000 B
  float* dinv    = (float*)(ws + 804096);        // 400,000 B
  unsigned short* Wt = (unsigned short*)(ws + 1204096);   // 106,496 B
  int*   csr_row = (int*)(ws + 1310720);         // 391*8192*4 = 12,812,288 B
  unsigned int* pairs = (unsigned int*)(ws + 14123008);   // 12,812,288 B
  unsigned short* hp  = (unsigned short*)(ws + 14123008); // 25,600,000 B (aliases pairs)

  hipMemsetAsync(bcnt, 0, NBUCK * sizeof(int), stream);
  hipMemsetAsync(d_out, 0, (size_t)out_size * sizeof(float), stream);

  bucket_k<<<(N_EDGES + ECH - 1) / ECH, 256, 0, stream>>>(row, col, bcnt, pairs);
  csr_build_k<<<NBUCK, 256, 0, stream>>>(pairs, bcnt, csr_row, offs, cnt, dinv);
  prep_wt_k<<<(HID * RKP + 255) / 256, 256, 0, stream>>>(W, Wt);
  gemm_k<<<(N_NODES + 63) / 64, 256, 0, stream>>>(x, Wt, dinv, hp);
  {
    int waves = (N_NODES + NPW - 1) / NPW;             // 6250
    int blocks = (waves * 64 + 255) / 256;             // 1563
    gather_k<<<blocks, 256, 0, stream>>>(
        hp, csr_row, offs, cnt, dinv, batch, b,
        (unsigned int*)(out + N_GRAPHS * NOUT));
  }
  logits_k<<<(N_GRAPHS * NOUT + 255) / 256, 256, 0, stream>>>(
      out + N_GRAPHS * NOUT, lin_W, lin_b, out);
}